// Round 9
// baseline (264.911 us; speedup 1.0000x reference)
//
#include <hip/hip_runtime.h>
#include <stdint.h>

#define M_DIM 16384
#define K_DIM 1024
#define N_DIM 4096
#define BM 128           // fallback tile
#define BN 128
#define LDSP 40          // fallback-path pad

#define TILE_ELEMS (128 * K_DIM)      // 131072 bf16 per 128-row packed tile

// ---- ring GEMM geometry ----------------------------------------------------
#define GBM 256
#define GBN 256
#define NSLAB 32            // K_DIM / 32
#define SLOT_E 16384        // elems per ring slot: 4 chunks x 4096 (32 KB)

typedef __bf16 bf16;
typedef __attribute__((ext_vector_type(8))) __bf16 bf16x8;
typedef __attribute__((ext_vector_type(4))) float f32x4;

// round-to-nearest-even fp32 -> bf16, packed two at a time (no NaN inputs)
__device__ __forceinline__ uint32_t pack2_bf16(float a, float b) {
    uint32_t ua = __float_as_uint(a);
    uint32_t ub = __float_as_uint(b);
    ua += 0x7fffu + ((ua >> 16) & 1u);
    ub += 0x7fffu + ((ub >> 16) & 1u);
    return (ua >> 16) | (ub & 0xffff0000u);
}

// ---- convert fp32 -> bf16 + repack into MFMA-fragment order (v3, frozen) ---
// Packed layout per 128-row tile: elem[(s*8+rb)*512 + lane*8 + j], with
// lane = q*16+lrow  <->  src row rb*16+lrow, col s*32+q*8+j.
__global__ __launch_bounds__(256) void convert_pack_kernel(
    const float* __restrict__ x, const float* __restrict__ w,
    bf16* __restrict__ xp, bf16* __restrict__ wp, float* __restrict__ out)
{
    const int t = threadIdx.x;
    const int g = blockIdx.x;
    if (g < (M_DIM / 256)) out[g * 256 + t] = 0.f;   // 64 blocks zero out[]

    const int W    = g * 4 + (t >> 6);   // wave id 0..5119
    const int lane = t & 63;
    const int tt   = W >> 5;             // packed tile 0..159 (128 x + 32 w)
    const int sub  = W & 31;
    const int rb   = sub & 7;            // 16-row block within tile
    const int s0   = (sub >> 3) * 8;     // s-octet base

    const float* src; bf16* dst;
    if (tt < (M_DIM / 128)) {
        src = x + (size_t)tt * 128 * K_DIM;
        dst = xp + (size_t)tt * TILE_ELEMS;
    } else {
        const int u = tt - (M_DIM / 128);
        src = w + (size_t)u * 128 * K_DIM;
        dst = wp + (size_t)u * TILE_ELEMS;
    }

    const int lrow = lane & 15, q = lane >> 4;
    const float* rsrc = src + (size_t)(rb * 16 + lrow) * K_DIM + q * 8;
    uint4* dst4 = (uint4*)dst;

    #pragma unroll
    for (int i = 0; i < 8; ++i) {
        const int s = s0 + i;
        float4 a = *(const float4*)(rsrc + s * 32);
        float4 b = *(const float4*)(rsrc + s * 32 + 4);
        uint4 v;
        v.x = pack2_bf16(a.x, a.y);
        v.y = pack2_bf16(a.z, a.w);
        v.z = pack2_bf16(b.x, b.y);
        v.w = pack2_bf16(b.z, b.w);
        dst4[(s * 8 + rb) * 64 + lane] = v;
    }
}

// ---- 256x256 ring-buffer GEMM (R2 verbatim) + XCD bijective swizzle --------
// BK=32 slabs; 4-slot LDS ring (32 KB each, 128 KB total); stage 2 slabs ahead.
// NEW (R9): bijective XCD swizzle [m204-form, nwg=1024 % 8 == 0]. Default
// round-robin gave each XCD 2 bx values but ALL 64 by values -> every XCD
// streamed the whole 32 MB A through its 4 MB L2 (FETCH 147 MB vs 42 MB
// working set). After swz = (b&7)*128 + b>>3, each XCD owns a contiguous
// by-range; ~32 concurrent blocks span ~2 by values -> A L2-resident &
// reused 16x, B (8 MB) L3-resident.

#define BAR() do { asm volatile("" ::: "memory"); \
                   __builtin_amdgcn_s_barrier();  \
                   asm volatile("" ::: "memory"); } while (0)
#define VMCNT4() asm volatile("s_waitcnt vmcnt(4)" ::: "memory")
#define VMCNT0() asm volatile("s_waitcnt vmcnt(0)" ::: "memory")

// stage one 8 KB chunk: wave w writes its 1 KB slice (lane x 16 B, linear)
#define STG(sl, ch, gsrc) \
    __builtin_amdgcn_global_load_lds( \
        (const __attribute__((address_space(1))) unsigned int*)(gsrc), \
        (__attribute__((address_space(3))) unsigned int*)&sm[(((sl) & 3) * SLOT_E) + (ch) * 4096 + w * 512], \
        16, 0, 0)

#define STG_A(t) do { STG(t, 0, Ag + (size_t)(t) * 4096 + toff); \
                      STG(t, 1, Ag + TILE_ELEMS + (size_t)(t) * 4096 + toff); } while (0)
#define STG_B(t) do { STG(t, 2, Bg + (size_t)(t) * 4096 + toff); \
                      STG(t, 3, Bg + TILE_ELEMS + (size_t)(t) * 4096 + toff); } while (0)

#define RD4(dst, base) do { \
    _Pragma("unroll") \
    for (int _i = 0; _i < 4; ++_i) \
        dst[_i] = *(const bf16x8*)&sm[(base) + _i * 512]; \
} while (0)

#define MFMA16X(Aset, Bset, IB) do { \
    __builtin_amdgcn_s_setprio(1); \
    _Pragma("unroll") \
    for (int ii = 0; ii < 4; ++ii) \
        _Pragma("unroll") \
        for (int jj = 0; jj < 4; ++jj) \
            acc[(IB) + ii][jj] = __builtin_amdgcn_mfma_f32_16x16x32_bf16( \
                Aset[ii], Bset[jj], acc[(IB) + ii][jj], 0, 0, 0); \
    __builtin_amdgcn_s_setprio(0); \
} while (0)

// CUR/NXT are token-pasted register-set suffixes (A or B)
#define SLAB(s, CUR, NXT) do { \
    if ((s) + 2 < NSLAB) STG_A((s) + 2); \
    RD4(Ahi, (((s) & 3) * SLOT_E) + aOff + 2048); \
    MFMA16X(Alo##CUR, Bv##CUR, 0); \
    if ((s) + 2 < NSLAB) STG_B((s) + 2); \
    if ((s) == NSLAB - 2) { VMCNT0(); } else if ((s) < NSLAB - 2) { VMCNT4(); } \
    BAR(); \
    if ((s) + 1 < NSLAB) { \
        RD4(Alo##NXT, ((((s) + 1) & 3) * SLOT_E) + aOff); \
        RD4(Bv##NXT,  ((((s) + 1) & 3) * SLOT_E) + bOff); \
    } \
    MFMA16X(Ahi, Bv##CUR, 4); \
} while (0)

__global__ __launch_bounds__(512, 2) void gemm_pool_ring_kernel(
    const bf16* __restrict__ xp, const bf16* __restrict__ wp,
    const float* __restrict__ bias, float* __restrict__ out)
{
    __shared__ bf16 sm[4 * SLOT_E];   // 128 KB

    // bijective XCD swizzle: nwg = 1024, nwg/8 = 128
    const int b   = blockIdx.x;
    const int swz = (b & 7) * 128 + (b >> 3);
    const int bx  = swz & (N_DIM / GBN - 1);   // 0..15 (fast within XCD: A L2-hot)
    const int by  = swz >> 4;                  // 0..63 (contiguous range per XCD)

    const int tid  = threadIdx.x;
    const int lane = tid & 63;
    const int w    = tid >> 6;      // wave 0..7
    const int wm   = w >> 2;        // M half: packed tile 2by+wm (rows wm*128..)
    const int wn   = w & 3;         // N quarter: cols wn*64..
    const int lr   = lane & 15;
    const int quad = lane >> 4;
    const int toff = tid * 8;       // staging: elem offset within a chunk

    const bf16* __restrict__ Ag = xp + (size_t)(2 * by) * TILE_ELEMS;
    const bf16* __restrict__ Bg = wp + (size_t)(2 * bx) * TILE_ELEMS;

    // ring-slot-relative fragment bases (elems)
    const int aOff = wm * 4096 + lane * 8;                             // chunks 0,1
    const int bOff = 8192 + (wn >> 1) * 4096 + (wn & 1) * 2048 + lane * 8; // chunks 2,3

    f32x4 acc[8][4] = {};
    bf16x8 AloA[4], AloB[4], Ahi[4], BvA[4], BvB[4];

    // prologue: stage slabs 0,1 (consumption order), wait slab 0, read phase-0 frags
    STG_A(0); STG_B(0);
    STG_A(1); STG_B(1);
    VMCNT4(); BAR();                 // slab 0 landed; slab 1 in flight
    RD4(AloA, aOff);                 // slot 0
    RD4(BvA,  bOff);

    #pragma unroll
    for (int sp = 0; sp < NSLAB / 2; ++sp) {
        SLAB(2 * sp,     A, B);
        SLAB(2 * sp + 1, B, A);
    }

    // fused epilogue: +bias, maxpool4 along N, row-sum, atomic out
    // C/D layout: col = lane&15, row = quad*4 + reg  [m89/m91]
    float bv[4];
    #pragma unroll
    for (int j = 0; j < 4; ++j)
        bv[j] = bias[bx * GBN + wn * 64 + j * 16 + lr];

    #pragma unroll
    for (int i = 0; i < 8; ++i) {
        float rs[4] = {0.f, 0.f, 0.f, 0.f};
        #pragma unroll
        for (int j = 0; j < 4; ++j) {
            #pragma unroll
            for (int r = 0; r < 4; ++r) {
                float v = acc[i][j][r] + bv[j];
                v = fmaxf(v, __shfl_xor(v, 1, 64));   // pool group = 4 adjacent cols
                v = fmaxf(v, __shfl_xor(v, 2, 64));
                rs[r] += v;
            }
        }
        #pragma unroll
        for (int r = 0; r < 4; ++r) {
            rs[r] += __shfl_xor(rs[r], 4, 64);        // one max per group summed
            rs[r] += __shfl_xor(rs[r], 8, 64);
        }
        if (lr == 0) {
            const int row = by * GBM + wm * 128 + i * 16 + quad * 4;
            #pragma unroll
            for (int r = 0; r < 4; ++r)
                atomicAdd(&out[row + r], rs[r] * 0.5f);
        }
    }
}

// ---- fallback (round-1 kernel) if ws too small -----------------------------
__global__ __launch_bounds__(256) void fused_linear_pool_kernel(
    const float* __restrict__ x, const float* __restrict__ wt,
    const float* __restrict__ bias, float* __restrict__ out)
{
    __shared__ uint32_t sA[BM * LDSP / 2];
    __shared__ uint32_t sB[BN * LDSP / 2];

    const int tid = threadIdx.x;
    const int bx = blockIdx.x;
    const int by = blockIdx.y;

    const float* Abase = x  + (size_t)by * BM * K_DIM;
    const float* Bbase = wt + (size_t)bx * BN * K_DIM;

    const int lane = tid & 63;
    const int wave = tid >> 6;
    const int wm = wave >> 1;
    const int wn = wave & 1;
    const int lr = lane & 15;
    const int quad = lane >> 4;

    const int srow  = tid >> 2;
    const int scol  = (tid & 3) * 8;
    const int swidx = (tid & 3) * 4;

    f32x4 acc[4][4] = {};

    for (int kt = 0; kt < K_DIM; kt += 32) {
        #pragma unroll
        for (int p = 0; p < 2; ++p) {
            const int r = srow + p * 64;
            const float4* ga = (const float4*)(Abase + (size_t)r * K_DIM + kt + scol);
            const float4* gb = (const float4*)(Bbase + (size_t)r * K_DIM + kt + scol);
            float4 a0 = ga[0], a1 = ga[1], b0 = gb[0], b1 = gb[1];
            uint4 wa;
            wa.x = pack2_bf16(a0.x, a0.y); wa.y = pack2_bf16(a0.z, a0.w);
            wa.z = pack2_bf16(a1.x, a1.y); wa.w = pack2_bf16(a1.z, a1.w);
            *(uint4*)&sA[r * (LDSP / 2) + swidx] = wa;
            uint4 wbv;
            wbv.x = pack2_bf16(b0.x, b0.y); wbv.y = pack2_bf16(b0.z, b0.w);
            wbv.z = pack2_bf16(b1.x, b1.y); wbv.w = pack2_bf16(b1.z, b1.w);
            *(uint4*)&sB[r * (LDSP / 2) + swidx] = wbv;
        }
        __syncthreads();

        bf16x8 af[4], bfr[4];
        #pragma unroll
        for (int i = 0; i < 4; ++i)
            af[i] = *(const bf16x8*)((const bf16*)sA + (wm * 64 + i * 16 + lr) * LDSP + quad * 8);
        #pragma unroll
        for (int j = 0; j < 4; ++j)
            bfr[j] = *(const bf16x8*)((const bf16*)sB + (wn * 64 + j * 16 + lr) * LDSP + quad * 8);

        #pragma unroll
        for (int i = 0; i < 4; ++i)
            #pragma unroll
            for (int j = 0; j < 4; ++j)
                acc[i][j] = __builtin_amdgcn_mfma_f32_16x16x32_bf16(af[i], bfr[j], acc[i][j], 0, 0, 0);
        __syncthreads();
    }

    float bv[4];
    #pragma unroll
    for (int j = 0; j < 4; ++j)
        bv[j] = bias[bx * BN + wn * 64 + j * 16 + lr];

    #pragma unroll
    for (int i = 0; i < 4; ++i) {
        float rsum[4] = {0.f, 0.f, 0.f, 0.f};
        #pragma unroll
        for (int j = 0; j < 4; ++j) {
            #pragma unroll
            for (int r = 0; r < 4; ++r) {
                float t = acc[i][j][r] + bv[j];
                t = fmaxf(t, __shfl_xor(t, 1, 64));
                t = fmaxf(t, __shfl_xor(t, 2, 64));
                t += __shfl_xor(t, 4, 64);
                t += __shfl_xor(t, 8, 64);
                rsum[r] += t;
            }
        }
        if (lr == 0) {
            const int row = by * BM + wm * 64 + i * 16 + quad * 4;
            #pragma unroll
            for (int r = 0; r < 4; ++r)
                atomicAdd(&out[row + r], rsum[r] * 0.5f);
        }
    }
}

extern "C" void kernel_launch(void* const* d_in, const int* in_sizes, int n_in,
                              void* d_out, int out_size, void* d_ws, size_t ws_size,
                              hipStream_t stream) {
    const float* x  = (const float*)d_in[0];
    const float* wt = (const float*)d_in[1];
    const float* bs = (const float*)d_in[2];
    float* out = (float*)d_out;

    const size_t xe = (size_t)M_DIM * K_DIM;
    const size_t we = (size_t)N_DIM * K_DIM;
    const size_t need = (xe + we) * sizeof(bf16);  // ~42 MB

    if (ws_size >= need) {
        bf16* xp = (bf16*)d_ws;
        bf16* wp = xp + xe;
        convert_pack_kernel<<<1280, 256, 0, stream>>>(x, wt, xp, wp, out);
        gemm_pool_ring_kernel<<<(M_DIM / GBM) * (N_DIM / GBN), 512, 0, stream>>>(xp, wp, bs, out);
    } else {
        hipMemsetAsync(out, 0, (size_t)out_size * sizeof(float), stream);
        dim3 grid(N_DIM / BN, M_DIM / BM);
        fused_linear_pool_kernel<<<grid, 256, 0, stream>>>(x, wt, bs, out);
    }
}

// Round 10
// 243.916 us; speedup vs baseline: 1.0861x; 1.0861x over previous
//
#include <hip/hip_runtime.h>
#include <stdint.h>

#define M_DIM 16384
#define K_DIM 1024
#define N_DIM 4096
#define BM 128           // fallback tile
#define BN 128
#define LDSP 40          // fallback-path pad

#define TILE_ELEMS (128 * K_DIM)      // 131072 bf16 per 128-row packed tile
#define SLAB_ELEMS (128 * 32)         // 4096 bf16 per (tile, s) slab
#define CPAD 516                       // convert LDS row stride (dwords)

// ---- ring GEMM geometry ----------------------------------------------------
#define GBM 256
#define GBN 256
#define NSLAB 32            // K_DIM / 32
#define SLOT_E 16384        // elems per ring slot: 4 chunks x 4096 (32 KB)

typedef __bf16 bf16;
typedef __attribute__((ext_vector_type(8))) __bf16 bf16x8;
typedef __attribute__((ext_vector_type(4))) float f32x4;

// round-to-nearest-even fp32 -> bf16, packed two at a time (no NaN inputs)
__device__ __forceinline__ uint32_t pack2_bf16(float a, float b) {
    uint32_t ua = __float_as_uint(a);
    uint32_t ub = __float_as_uint(b);
    ua += 0x7fffu + ((ua >> 16) & 1u);
    ub += 0x7fffu + ((ub >> 16) & 1u);
    return (ua >> 16) | (ub & 0xffff0000u);
}

// ---- convert fp32 -> bf16 + repack into MFMA-fragment order (R2 version) ---
// Packed layout per 128-row tile: [s:32][rb:8][lane:64][j:8], lane = q*16+lrow,
// src row = rb*16 + lrow, src col = s*32 + q*8 + j.
// Two-phase: 16 coalesced row reads -> LDS -> fragment-order stores.
__global__ __launch_bounds__(256) void convert_pack_kernel(
    const float* __restrict__ x, const float* __restrict__ w,
    bf16* __restrict__ xp, bf16* __restrict__ wp, float* __restrict__ out)
{
    int g = blockIdx.x;
    const int t = threadIdx.x;
    if (g < (M_DIM / 256)) out[g * 256 + t] = 0.f;   // 64 blocks zero out[]

    const float* src;
    bf16* dst;
    if (g < (M_DIM / 16)) {
        src = x + (size_t)g * 16 * K_DIM;  dst = xp;
    } else {
        g -= M_DIM / 16;
        src = w + (size_t)g * 16 * K_DIM;  dst = wp;
    }
    const int tile = g >> 3;
    const int rb   = g & 7;

    __shared__ uint32_t ls[16 * CPAD];   // ~33 KB

    #pragma unroll
    for (int i = 0; i < 16; ++i) {
        float4 v = ((const float4*)src)[i * 256 + t];
        uint2 d;
        d.x = pack2_bf16(v.x, v.y);
        d.y = pack2_bf16(v.z, v.w);
        *(uint2*)&ls[i * CPAD + t * 2] = d;
    }
    __syncthreads();

    const int wv = t >> 6, l = t & 63;
    const int lrow = l & 15, q = l >> 4;
    uint4* dst4 = (uint4*)(dst + (size_t)tile * TILE_ELEMS);
    #pragma unroll
    for (int it = 0; it < 8; ++it) {
        const int s = wv + it * 4;
        uint4 v = *(const uint4*)&ls[lrow * CPAD + s * 16 + q * 4];
        dst4[(s * 8 + rb) * 64 + l] = v;
    }
}

// ---- 256x256 ring-buffer GEMM (R2 verbatim — best measured: 143 µs) --------
// BK=32 slabs; 4-slot LDS ring (32 KB each, 128 KB total); stage 2 slabs ahead.
// Per slab: {stage A(s+2); read Ahi(s); MFMA(Alo,B)(s);
//            stage B(s+2); vmcnt(4); barrier; read Alo/B(s+1); MFMA(Ahi,B)(s)}.
// vmcnt(4): outstanding = 4 (slab s+1) + 4 (slab s+2); retires s+1 only.
// No XCD swizzle: R9 measured it FETCH-neutral and 24% slower (dispatch
// mapping assumption wrong; natural bx-fast order already gives A locality).

#define BAR() do { asm volatile("" ::: "memory"); \
                   __builtin_amdgcn_s_barrier();  \
                   asm volatile("" ::: "memory"); } while (0)
#define VMCNT4() asm volatile("s_waitcnt vmcnt(4)" ::: "memory")
#define VMCNT0() asm volatile("s_waitcnt vmcnt(0)" ::: "memory")

// stage one 8 KB chunk: wave w writes its 1 KB slice (lane x 16 B, linear)
#define STG(sl, ch, gsrc) \
    __builtin_amdgcn_global_load_lds( \
        (const __attribute__((address_space(1))) unsigned int*)(gsrc), \
        (__attribute__((address_space(3))) unsigned int*)&sm[(((sl) & 3) * SLOT_E) + (ch) * 4096 + w * 512], \
        16, 0, 0)

#define STG_A(t) do { STG(t, 0, Ag + (size_t)(t) * 4096 + toff); \
                      STG(t, 1, Ag + TILE_ELEMS + (size_t)(t) * 4096 + toff); } while (0)
#define STG_B(t) do { STG(t, 2, Bg + (size_t)(t) * 4096 + toff); \
                      STG(t, 3, Bg + TILE_ELEMS + (size_t)(t) * 4096 + toff); } while (0)

#define RD4(dst, base) do { \
    _Pragma("unroll") \
    for (int _i = 0; _i < 4; ++_i) \
        dst[_i] = *(const bf16x8*)&sm[(base) + _i * 512]; \
} while (0)

#define MFMA16X(Aset, Bset, IB) do { \
    __builtin_amdgcn_s_setprio(1); \
    _Pragma("unroll") \
    for (int ii = 0; ii < 4; ++ii) \
        _Pragma("unroll") \
        for (int jj = 0; jj < 4; ++jj) \
            acc[(IB) + ii][jj] = __builtin_amdgcn_mfma_f32_16x16x32_bf16( \
                Aset[ii], Bset[jj], acc[(IB) + ii][jj], 0, 0, 0); \
    __builtin_amdgcn_s_setprio(0); \
} while (0)

// CUR/NXT are token-pasted register-set suffixes (A or B)
#define SLAB(s, CUR, NXT) do { \
    if ((s) + 2 < NSLAB) STG_A((s) + 2); \
    RD4(Ahi, (((s) & 3) * SLOT_E) + aOff + 2048); \
    MFMA16X(Alo##CUR, Bv##CUR, 0); \
    if ((s) + 2 < NSLAB) STG_B((s) + 2); \
    if ((s) == NSLAB - 2) { VMCNT0(); } else if ((s) < NSLAB - 2) { VMCNT4(); } \
    BAR(); \
    if ((s) + 1 < NSLAB) { \
        RD4(Alo##NXT, ((((s) + 1) & 3) * SLOT_E) + aOff); \
        RD4(Bv##NXT,  ((((s) + 1) & 3) * SLOT_E) + bOff); \
    } \
    MFMA16X(Ahi, Bv##CUR, 4); \
} while (0)

__global__ __launch_bounds__(512, 2) void gemm_pool_ring_kernel(
    const bf16* __restrict__ xp, const bf16* __restrict__ wp,
    const float* __restrict__ bias, float* __restrict__ out)
{
    __shared__ bf16 sm[4 * SLOT_E];   // 128 KB

    const int b  = blockIdx.x;
    const int bx = b & (N_DIM / GBN - 1);   // 0..15 (fast: A tile reused across bx)
    const int by = b >> 4;                  // 0..63

    const int tid  = threadIdx.x;
    const int lane = tid & 63;
    const int w    = tid >> 6;      // wave 0..7
    const int wm   = w >> 2;        // M half: packed tile 2by+wm (rows wm*128..)
    const int wn   = w & 3;         // N quarter: cols wn*64..
    const int lr   = lane & 15;
    const int quad = lane >> 4;
    const int toff = tid * 8;       // staging: elem offset within a chunk

    const bf16* __restrict__ Ag = xp + (size_t)(2 * by) * TILE_ELEMS;
    const bf16* __restrict__ Bg = wp + (size_t)(2 * bx) * TILE_ELEMS;

    // ring-slot-relative fragment bases (elems)
    const int aOff = wm * 4096 + lane * 8;                             // chunks 0,1
    const int bOff = 8192 + (wn >> 1) * 4096 + (wn & 1) * 2048 + lane * 8; // chunks 2,3

    f32x4 acc[8][4] = {};
    bf16x8 AloA[4], AloB[4], Ahi[4], BvA[4], BvB[4];

    // prologue: stage slabs 0,1 (consumption order), wait slab 0, read phase-0 frags
    STG_A(0); STG_B(0);
    STG_A(1); STG_B(1);
    VMCNT4(); BAR();                 // slab 0 landed; slab 1 in flight
    RD4(AloA, aOff);                 // slot 0
    RD4(BvA,  bOff);

    #pragma unroll
    for (int sp = 0; sp < NSLAB / 2; ++sp) {
        SLAB(2 * sp,     A, B);
        SLAB(2 * sp + 1, B, A);
    }

    // fused epilogue: +bias, maxpool4 along N, row-sum, atomic out
    // C/D layout: col = lane&15, row = quad*4 + reg  [m89/m91]
    float bv[4];
    #pragma unroll
    for (int j = 0; j < 4; ++j)
        bv[j] = bias[bx * GBN + wn * 64 + j * 16 + lr];

    #pragma unroll
    for (int i = 0; i < 8; ++i) {
        float rs[4] = {0.f, 0.f, 0.f, 0.f};
        #pragma unroll
        for (int j = 0; j < 4; ++j) {
            #pragma unroll
            for (int r = 0; r < 4; ++r) {
                float v = acc[i][j][r] + bv[j];
                v = fmaxf(v, __shfl_xor(v, 1, 64));   // pool group = 4 adjacent cols
                v = fmaxf(v, __shfl_xor(v, 2, 64));
                rs[r] += v;
            }
        }
        #pragma unroll
        for (int r = 0; r < 4; ++r) {
            rs[r] += __shfl_xor(rs[r], 4, 64);        // one max per group summed
            rs[r] += __shfl_xor(rs[r], 8, 64);
        }
        if (lr == 0) {
            const int row = by * GBM + wm * 128 + i * 16 + quad * 4;
            #pragma unroll
            for (int r = 0; r < 4; ++r)
                atomicAdd(&out[row + r], rs[r] * 0.5f);
        }
    }
}

// ---- fallback (round-1 kernel) if ws too small -----------------------------
__global__ __launch_bounds__(256) void fused_linear_pool_kernel(
    const float* __restrict__ x, const float* __restrict__ wt,
    const float* __restrict__ bias, float* __restrict__ out)
{
    __shared__ uint32_t sA[BM * LDSP / 2];
    __shared__ uint32_t sB[BN * LDSP / 2];

    const int tid = threadIdx.x;
    const int bx = blockIdx.x;
    const int by = blockIdx.y;

    const float* Abase = x  + (size_t)by * BM * K_DIM;
    const float* Bbase = wt + (size_t)bx * BN * K_DIM;

    const int lane = tid & 63;
    const int wave = tid >> 6;
    const int wm = wave >> 1;
    const int wn = wave & 1;
    const int lr = lane & 15;
    const int quad = lane >> 4;

    const int srow  = tid >> 2;
    const int scol  = (tid & 3) * 8;
    const int swidx = (tid & 3) * 4;

    f32x4 acc[4][4] = {};

    for (int kt = 0; kt < K_DIM; kt += 32) {
        #pragma unroll
        for (int p = 0; p < 2; ++p) {
            const int r = srow + p * 64;
            const float4* ga = (const float4*)(Abase + (size_t)r * K_DIM + kt + scol);
            const float4* gb = (const float4*)(Bbase + (size_t)r * K_DIM + kt + scol);
            float4 a0 = ga[0], a1 = ga[1], b0 = gb[0], b1 = gb[1];
            uint4 wa;
            wa.x = pack2_bf16(a0.x, a0.y); wa.y = pack2_bf16(a0.z, a0.w);
            wa.z = pack2_bf16(a1.x, a1.y); wa.w = pack2_bf16(a1.z, a1.w);
            *(uint4*)&sA[r * (LDSP / 2) + swidx] = wa;
            uint4 wbv;
            wbv.x = pack2_bf16(b0.x, b0.y); wbv.y = pack2_bf16(b0.z, b0.w);
            wbv.z = pack2_bf16(b1.x, b1.y); wbv.w = pack2_bf16(b1.z, b1.w);
            *(uint4*)&sB[r * (LDSP / 2) + swidx] = wbv;
        }
        __syncthreads();

        bf16x8 af[4], bfr[4];
        #pragma unroll
        for (int i = 0; i < 4; ++i)
            af[i] = *(const bf16x8*)((const bf16*)sA + (wm * 64 + i * 16 + lr) * LDSP + quad * 8);
        #pragma unroll
        for (int j = 0; j < 4; ++j)
            bfr[j] = *(const bf16x8*)((const bf16*)sB + (wn * 64 + j * 16 + lr) * LDSP + quad * 8);

        #pragma unroll
        for (int i = 0; i < 4; ++i)
            #pragma unroll
            for (int j = 0; j < 4; ++j)
                acc[i][j] = __builtin_amdgcn_mfma_f32_16x16x32_bf16(af[i], bfr[j], acc[i][j], 0, 0, 0);
        __syncthreads();
    }

    float bv[4];
    #pragma unroll
    for (int j = 0; j < 4; ++j)
        bv[j] = bias[bx * BN + wn * 64 + j * 16 + lr];

    #pragma unroll
    for (int i = 0; i < 4; ++i) {
        float rsum[4] = {0.f, 0.f, 0.f, 0.f};
        #pragma unroll
        for (int j = 0; j < 4; ++j) {
            #pragma unroll
            for (int r = 0; r < 4; ++r) {
                float t = acc[i][j][r] + bv[j];
                t = fmaxf(t, __shfl_xor(t, 1, 64));
                t = fmaxf(t, __shfl_xor(t, 2, 64));
                t += __shfl_xor(t, 4, 64);
                t += __shfl_xor(t, 8, 64);
                rsum[r] += t;
            }
        }
        if (lr == 0) {
            const int row = by * BM + wm * 64 + i * 16 + quad * 4;
            #pragma unroll
            for (int r = 0; r < 4; ++r)
                atomicAdd(&out[row + r], rsum[r] * 0.5f);
        }
    }
}

extern "C" void kernel_launch(void* const* d_in, const int* in_sizes, int n_in,
                              void* d_out, int out_size, void* d_ws, size_t ws_size,
                              hipStream_t stream) {
    const float* x  = (const float*)d_in[0];
    const float* wt = (const float*)d_in[1];
    const float* bs = (const float*)d_in[2];
    float* out = (float*)d_out;

    const size_t xe = (size_t)M_DIM * K_DIM;
    const size_t we = (size_t)N_DIM * K_DIM;
    const size_t need = (xe + we) * sizeof(bf16);  // ~42 MB

    if (ws_size >= need) {
        bf16* xp = (bf16*)d_ws;
        bf16* wp = xp + xe;
        const int nconv = (M_DIM / 16) + (N_DIM / 16);   // 1024 + 256 = 1280
        convert_pack_kernel<<<nconv, 256, 0, stream>>>(x, wt, xp, wp, out);
        gemm_pool_ring_kernel<<<(M_DIM / GBM) * (N_DIM / GBN), 512, 0, stream>>>(xp, wp, bs, out);
    } else {
        hipMemsetAsync(out, 0, (size_t)out_size * sizeof(float), stream);
        dim3 grid(N_DIM / BN, M_DIM / BM);
        fused_linear_pool_kernel<<<grid, 256, 0, stream>>>(x, wt, bs, out);
    }
}